// Round 1
// baseline (121.979 us; speedup 1.0000x reference)
//
#include <hip/hip_runtime.h>

#define BATCH 4096
#define FEAT 512
#define NUM_CLASSES 10000

// Seed the accumulator with the exact "clip floor" background term:
// (B*C - B) entries of 1e-12, divided by B  ->  (C-1)*1e-12
__global__ void center_loss_init(float* __restrict__ out) {
    out[0] = (float)((double)(NUM_CLASSES - 1) * 1e-12);
}

// One wave (64 lanes) per batch row. 512 floats/row = 128 float4 = 2 float4/lane.
__global__ __launch_bounds__(256) void center_loss_kernel(
    const float* __restrict__ x,
    const int* __restrict__ labels,
    const float* __restrict__ centers,
    float* __restrict__ out) {
    const int wave = threadIdx.x >> 6;          // 0..3 (4 waves per block)
    const int lane = threadIdx.x & 63;
    const int row  = blockIdx.x * 4 + wave;     // 0..BATCH-1
    if (row >= BATCH) return;

    const int lbl = labels[row];
    const float4* __restrict__ xr = (const float4*)(x + (size_t)row * FEAT);
    const float4* __restrict__ cr = (const float4*)(centers + (size_t)lbl * FEAT);

    float acc = 0.0f;
#pragma unroll
    for (int i = 0; i < 2; ++i) {
        float4 a = xr[lane + i * 64];
        float4 c = cr[lane + i * 64];
        float d0 = a.x - c.x;
        float d1 = a.y - c.y;
        float d2 = a.z - c.z;
        float d3 = a.w - c.w;
        acc += d0 * d0 + d1 * d1 + d2 * d2 + d3 * d3;
    }

    // 64-lane shuffle reduction
#pragma unroll
    for (int off = 32; off > 0; off >>= 1)
        acc += __shfl_down(acc, off, 64);

    if (lane == 0) {
        // clip BEFORE the /B scale, faithful to the reference
        float v = fminf(fmaxf(acc, 1e-12f), 1e12f);
        atomicAdd(out, v * (1.0f / (float)BATCH));
    }
}

extern "C" void kernel_launch(void* const* d_in, const int* in_sizes, int n_in,
                              void* d_out, int out_size, void* d_ws, size_t ws_size,
                              hipStream_t stream) {
    const float* x       = (const float*)d_in[0];
    const int*   labels  = (const int*)d_in[1];
    const float* centers = (const float*)d_in[2];
    float* out = (float*)d_out;

    center_loss_init<<<1, 1, 0, stream>>>(out);
    center_loss_kernel<<<BATCH / 4, 256, 0, stream>>>(x, labels, centers, out);
}

// Round 2
// 74.166 us; speedup vs baseline: 1.6447x; 1.6447x over previous
//
#include <hip/hip_runtime.h>

#define BATCH 4096
#define FEAT 512
#define NUM_CLASSES 10000

// Stage 1: one wave (64 lanes) per batch row -> squared distance to its center.
// Writes per-row partial to ws[row]. No atomics.
__global__ __launch_bounds__(256) void center_loss_dist(
    const float* __restrict__ x,
    const int* __restrict__ labels,
    const float* __restrict__ centers,
    float* __restrict__ ws) {
    const int wave = threadIdx.x >> 6;          // 0..3
    const int lane = threadIdx.x & 63;
    const int row  = blockIdx.x * 4 + wave;

    const int lbl = labels[row];
    const float4* __restrict__ xr = (const float4*)(x + (size_t)row * FEAT);
    const float4* __restrict__ cr = (const float4*)(centers + (size_t)lbl * FEAT);

    // 512 floats = 128 float4 = 2 float4/lane
    float4 a0 = xr[lane];
    float4 a1 = xr[lane + 64];
    float4 c0 = cr[lane];
    float4 c1 = cr[lane + 64];

    float d0 = a0.x - c0.x, d1 = a0.y - c0.y, d2 = a0.z - c0.z, d3 = a0.w - c0.w;
    float e0 = a1.x - c1.x, e1 = a1.y - c1.y, e2 = a1.z - c1.z, e3 = a1.w - c1.w;
    float acc = d0 * d0 + d1 * d1 + d2 * d2 + d3 * d3
              + e0 * e0 + e1 * e1 + e2 * e2 + e3 * e3;

#pragma unroll
    for (int off = 32; off > 0; off >>= 1)
        acc += __shfl_down(acc, off, 64);

    if (lane == 0) ws[row] = acc;
}

// Stage 2: single block reduces the 4096 partials (clip each, sum, scale)
// and adds the exact clip-floor background term (B*C - B)*1e-12 / B.
__global__ __launch_bounds__(1024) void center_loss_reduce(
    const float* __restrict__ ws,
    float* __restrict__ out) {
    const int tid = threadIdx.x;
    const float4 v = ((const float4*)ws)[tid];   // 1024 threads * 4 = 4096

    float s = fminf(fmaxf(v.x, 1e-12f), 1e12f)
            + fminf(fmaxf(v.y, 1e-12f), 1e12f)
            + fminf(fmaxf(v.z, 1e-12f), 1e12f)
            + fminf(fmaxf(v.w, 1e-12f), 1e12f);

#pragma unroll
    for (int off = 32; off > 0; off >>= 1)
        s += __shfl_down(s, off, 64);

    __shared__ float warp_sums[16];
    const int wave = tid >> 6;
    const int lane = tid & 63;
    if (lane == 0) warp_sums[wave] = s;
    __syncthreads();

    if (wave == 0) {
        float t = (lane < 16) ? warp_sums[lane] : 0.0f;
#pragma unroll
        for (int off = 8; off > 0; off >>= 1)
            t += __shfl_down(t, off, 64);
        if (lane == 0) {
            out[0] = t * (1.0f / (float)BATCH)
                   + (float)((double)(NUM_CLASSES - 1) * 1e-12);
        }
    }
}

extern "C" void kernel_launch(void* const* d_in, const int* in_sizes, int n_in,
                              void* d_out, int out_size, void* d_ws, size_t ws_size,
                              hipStream_t stream) {
    const float* x       = (const float*)d_in[0];
    const int*   labels  = (const int*)d_in[1];
    const float* centers = (const float*)d_in[2];
    float* out = (float*)d_out;
    float* ws  = (float*)d_ws;

    center_loss_dist<<<BATCH / 4, 256, 0, stream>>>(x, labels, centers, ws);
    center_loss_reduce<<<1, 1024, 0, stream>>>(ws, out);
}